// Round 16
// baseline (190.765 us; speedup 1.0000x reference)
//
#include <hip/hip_runtime.h>
#include <hip/hip_bf16.h>
#include <math.h>

// Problem constants
#define BB 512
#define SS 32
#define DD 256
#define HH 4
#define DHH 64
#define PP 3
#define EE 8
#define KTOP 2
#define HID 1024
#define TT (BB*SS)          // 16384
#define CAP 8192            // 2*T*K/E
#define TD ((size_t)TT*DD)  // 4194304

typedef short short8 __attribute__((ext_vector_type(8)));
typedef float f32x4 __attribute__((ext_vector_type(4)));

#define GLL(gp, lp) __builtin_amdgcn_global_load_lds( \
    (const __attribute__((address_space(1))) void*)(gp), \
    (__attribute__((address_space(3))) void*)(lp), 16, 0, 0)

#define MFMA16(A, B, C) __builtin_amdgcn_mfma_f32_16x16x32_bf16(A, B, C, 0, 0, 0)

__device__ __forceinline__ float wred(float v) {
#pragma unroll
  for (int off = 32; off; off >>= 1) v += __shfl_xor(v, off, 64);
  return v;
}

__device__ __forceinline__ float f4c(const float4& f, int u) {
  return (u == 0) ? f.x : (u == 1) ? f.y : (u == 2) ? f.z : f.w;
}

__device__ __forceinline__ unsigned short f2b(float f) {
  union { float f; unsigned u; } x; x.f = f;
  unsigned r = x.u + 0x7fffu + ((x.u >> 16) & 1u);
  return (unsigned short)(r >> 16);
}

__device__ __forceinline__ float b2f(unsigned short u) {
  union { unsigned u; float f; } x; x.u = ((unsigned)u) << 16;
  return x.f;
}

__device__ __forceinline__ unsigned cvt_pk_bf16(float lo, float hi) {
  unsigned r;
  asm("v_cvt_pk_bf16_f32 %0, %1, %2" : "=v"(r) : "v"(lo), "v"(hi));
  return r;
}

// tanh-approx gelu, exp2 form
__device__ __forceinline__ float gelu_f(float x) {
  float x2 = x * x;
  float t2 = x * __builtin_fmaf(x2, 0.102943842f, 2.30212326f);
  float e = __builtin_amdgcn_exp2f(t2);
  float r = __builtin_amdgcn_rcpf(e + 1.f);
  float th = __builtin_fmaf(-2.f, r, 1.f);
  return 0.5f * x * (1.f + th);
}

// ---------------- fused prep: weight cvts + pos-attn + LN1-split ----------------
// blocks [0,1024): ew1 cvt; [1024,2048): ew2 cvt; [2048,2144): qkv w cvt;
// [2144,2176): out w cvt; [2176,2688): pos; [2688,6784): LN1+split
__global__ void k_prep(
    const float* __restrict__ ew1, unsigned short* __restrict__ w1s,
    const float* __restrict__ ew2, unsigned short* __restrict__ w2s,
    const float* __restrict__ qw, const float* __restrict__ kw,
    const float* __restrict__ vw, unsigned short* __restrict__ wqkvf,
    const float* __restrict__ outw, unsigned short* __restrict__ woutf,
    const float* __restrict__ pos, const float* __restrict__ p1w,
    const float* __restrict__ p1b, const float* __restrict__ p2w,
    const float* __restrict__ p2b, const float* __restrict__ headw,
    float* __restrict__ pa,
    const float* __restrict__ x, const float* __restrict__ ln1w,
    const float* __restrict__ ln1b, unsigned short* __restrict__ rhi,
    unsigned short* __restrict__ rlo) {
  __shared__ float shbuf[2*HH*SS];
  int bid = blockIdx.x;
  int tid = threadIdx.x;
  if (bid < 2048) {
    const float* src = (bid < 1024) ? ew1 : ew2;
    unsigned short* dst = (bid < 1024) ? w1s : w2s;
    int K = (bid < 1024) ? DD : HID;
    int N = (bid < 1024) ? HID : DD;
    int idx = (bid & 1023) * 256 + tid;
    int lane = idx & 63;
    int tile = idx >> 6;
    int ntn = N >> 4;
    int ntk = K >> 5;
    int e = tile / (ntk * ntn);
    int rem = tile - e * (ntk * ntn);
    int kt = rem / ntn;
    int nt = rem - kt * ntn;
    int g = lane >> 4, c = lane & 15;
    const float* s = src + ((size_t)e * K + kt*32 + g*8) * N + nt*16 + c;
    short8 frag;
#pragma unroll
    for (int j = 0; j < 8; ++j) frag[j] = (short)f2b(s[(size_t)j * N]);
    reinterpret_cast<short8*>(dst)[(size_t)tile * 64 + lane] = frag;
  } else if (bid < 2144) {
    int tile = (bid - 2048) * 4 + (tid >> 6);   // kt*48 + nt
    int lane = tid & 63;
    int kt = tile / 48, nt = tile % 48;
    int c = lane & 15, g = lane >> 4;
    const float* W = (nt < 16) ? qw : (nt < 32) ? kw : vw;
    int col = (nt & 15) * 16 + c;
    const float* s = W + ((size_t)kt*32 + g*8)*DD + col;
    short8 hi, lo;
#pragma unroll
    for (int j = 0; j < 8; ++j) {
      float xx = s[(size_t)j * DD];
      unsigned short hb = f2b(xx);
      hi[j] = (short)hb;
      lo[j] = (short)f2b(xx - b2f(hb));
    }
    short8* d = reinterpret_cast<short8*>(wqkvf);
    d[(size_t)tile*128 + lane] = hi;
    d[(size_t)tile*128 + 64 + lane] = lo;
  } else if (bid < 2176) {
    int tile = (bid - 2144) * 4 + (tid >> 6);   // kt*16 + nt
    int lane = tid & 63;
    int kt = tile >> 4, nt = tile & 15;
    int c = lane & 15, g = lane >> 4;
    int col = nt * 16 + c;
    const float* s = outw + ((size_t)kt*32 + g*8)*DD + col;
    short8 hi, lo;
#pragma unroll
    for (int j = 0; j < 8; ++j) {
      float xx = s[(size_t)j * DD];
      unsigned short hb = f2b(xx);
      hi[j] = (short)hb;
      lo[j] = (short)f2b(xx - b2f(hb));
    }
    short8* d = reinterpret_cast<short8*>(woutf);
    d[(size_t)tile*128 + lane] = hi;
    d[(size_t)tile*128 + 64 + lane] = lo;
  } else if (bid < 2688) {
    int b = bid - 2176;
    float* ph = shbuf;
    float* ex = shbuf + HH*SS;
    if (tid < 128) {
      int s = tid >> 2, hd = tid & 3;
      const float* pp = pos + ((size_t)b * SS + s) * PP;
      float p0 = pp[0], p1 = pp[1], p2 = pp[2];
      float t0 = fmaxf(0.f, p0*p1w[0] + p1*p1w[3] + p2*p1w[6] + p1b[0]);
      float t1 = fmaxf(0.f, p0*p1w[1] + p1*p1w[4] + p2*p1w[7] + p1b[1]);
      float t2 = fmaxf(0.f, p0*p1w[2] + p1*p1w[5] + p2*p1w[8] + p1b[2]);
      float acc = 0.f;
#pragma unroll
      for (int c = 0; c < 32; ++c) {
        float pf = t0*p2w[c] + t1*p2w[32+c] + t2*p2w[64+c] + p2b[c];
        acc += pf * headw[c*4 + hd];
      }
      ph[hd*SS + s] = acc;
    }
    __syncthreads();
    if (tid < 4) {
      int h2 = tid;
      float mx = -1e30f;
      for (int j = 0; j < 32; ++j) mx = fmaxf(mx, -ph[h2*SS + j]);
      float sum = 0.f;
      for (int j = 0; j < 32; ++j) { float e = expf(-ph[h2*SS + j] - mx); ex[h2*SS + j] = e; sum += e; }
      float inv = 1.f / sum;
      for (int j = 0; j < 32; ++j) pa[((size_t)b*HH + h2)*SS + j] = ex[h2*SS + j] * inv;
    }
  } else {
    int t = (bid - 2688) * 4 + (tid >> 6);
    int lane = tid & 63;
    float4 xv = reinterpret_cast<const float4*>(x + (size_t)t * DD)[lane];
    float s1 = xv.x + xv.y + xv.z + xv.w;
    float s2 = xv.x*xv.x + xv.y*xv.y + xv.z*xv.z + xv.w*xv.w;
    s1 = wred(s1); s2 = wred(s2);
    float m = s1 * (1.f/256.f);
    float var = s2 * (1.f/256.f) - m*m;
    float rs = rsqrtf(var + 1e-6f);
    float4 wv = reinterpret_cast<const float4*>(ln1w)[lane];
    float4 bv = reinterpret_cast<const float4*>(ln1b)[lane];
    float4 o;
    o.x = (xv.x-m)*rs*wv.x + bv.x;
    o.y = (xv.y-m)*rs*wv.y + bv.y;
    o.z = (xv.z-m)*rs*wv.z + bv.z;
    o.w = (xv.w-m)*rs*wv.w + bv.w;
    ushort4 h4, l4;
    h4.x = f2b(o.x); l4.x = f2b(o.x - b2f(h4.x));
    h4.y = f2b(o.y); l4.y = f2b(o.y - b2f(h4.y));
    h4.z = f2b(o.z); l4.z = f2b(o.z - b2f(h4.z));
    h4.w = f2b(o.w); l4.w = f2b(o.w - b2f(h4.w));
    *reinterpret_cast<ushort4*>(rhi + (size_t)t * DD + lane*4) = h4;
    *reinterpret_cast<ushort4*>(rlo + (size_t)t * DD + lane*4) = l4;
  }
}

// ---------------- QKV via split-bf16 MFMA, M=32; A gathered per-lane via GLL ----------------
__global__ __launch_bounds__(512, 4) void k_qkvm(
    const unsigned short* __restrict__ hr, const unsigned short* __restrict__ lr,
    const unsigned short* __restrict__ wqkvf,
    float* __restrict__ q, float* __restrict__ k, float* __restrict__ v) {
  __shared__ short8 AF[2048];             // 32KB: 2 mt x (hi 8 + lo 8 kt) x 64
  int tid = threadIdx.x, lane = tid & 63, w = tid >> 6;
  int c = lane & 15, g = lane >> 4;
#pragma unroll
  for (int i = 0; i < 4; ++i) {
    int comb = i*8 + w;                   // 0..31
    int mt = comb >> 4, slot = comb & 15;
    int kt = slot & 7;
    const unsigned short* src = (slot < 8) ? hr : lr;
    const unsigned short* sp = src + ((size_t)(blockIdx.x*32 + mt*16 + c)*DD + kt*32 + g*8);
    GLL(sp, AF + comb*64);
  }
  const short8* wfv = reinterpret_cast<const short8*>(wqkvf);
  f32x4 acc[2][6] = {};
  __syncthreads();
#pragma unroll
  for (int kt = 0; kt < 8; ++kt) {
    short8 bh[6], bl[6];
#pragma unroll
    for (int n = 0; n < 6; ++n) {
      const short8* bp = wfv + ((size_t)kt*48 + w*6 + n)*128;
      bh[n] = bp[lane]; bl[n] = bp[64 + lane];
    }
    short8 ah[2], al[2];
#pragma unroll
    for (int mt = 0; mt < 2; ++mt) {
      ah[mt] = AF[(mt*16 + kt)*64 + lane];
      al[mt] = AF[(mt*16 + 8 + kt)*64 + lane];
    }
    __builtin_amdgcn_s_setprio(1);
#pragma unroll
    for (int n = 0; n < 6; ++n)
#pragma unroll
      for (int mt = 0; mt < 2; ++mt) {
        acc[mt][n] = MFMA16(ah[mt], bh[n], acc[mt][n]);
        acc[mt][n] = MFMA16(al[mt], bh[n], acc[mt][n]);
        acc[mt][n] = MFMA16(ah[mt], bl[n], acc[mt][n]);
      }
    __builtin_amdgcn_s_setprio(0);
  }
#pragma unroll
  for (int n = 0; n < 6; ++n) {
    int col = w*96 + n*16 + c;
    int wsel = col >> 8, cc = col & 255;
    int hd = cc >> 6, d2 = cc & 63;
    float* OUT = (wsel == 0) ? q : (wsel == 1) ? k : v;
#pragma unroll
    for (int mt = 0; mt < 2; ++mt) {
#pragma unroll
      for (int r = 0; r < 4; ++r) {
        int tok = (blockIdx.x*2 + mt)*16 + g*4 + r;
        int b = tok >> 5, s = tok & 31;
        OUT[(((size_t)b*HH + hd)*SS + s)*DHH + d2] = acc[mt][n][r];
      }
    }
  }
}

// ---------------- out-proj via split-bf16 MFMA + residual, M=32, GLL gather ----------------
__global__ __launch_bounds__(512, 4) void k_outm(
    const unsigned short* __restrict__ hr, const unsigned short* __restrict__ lr,
    const unsigned short* __restrict__ wof,
    const float* __restrict__ xres, const float* __restrict__ bias,
    float* __restrict__ out) {
  __shared__ short8 AF[2048];             // 32KB
  int tid = threadIdx.x, lane = tid & 63, w = tid >> 6;
  int c = lane & 15, g = lane >> 4;
#pragma unroll
  for (int i = 0; i < 4; ++i) {
    int comb = i*8 + w;
    int mt = comb >> 4, slot = comb & 15;
    int kt = slot & 7;
    const unsigned short* src = (slot < 8) ? hr : lr;
    const unsigned short* sp = src + ((size_t)(blockIdx.x*32 + mt*16 + c)*DD + kt*32 + g*8);
    GLL(sp, AF + comb*64);
  }
  const short8* wfv = reinterpret_cast<const short8*>(wof);
  f32x4 acc[2][2] = {};
  __syncthreads();
#pragma unroll
  for (int kt = 0; kt < 8; ++kt) {
    short8 bh[2], bl[2];
#pragma unroll
    for (int n = 0; n < 2; ++n) {
      const short8* bp = wfv + ((size_t)kt*16 + w*2 + n)*128;
      bh[n] = bp[lane]; bl[n] = bp[64 + lane];
    }
    short8 ah[2], al[2];
#pragma unroll
    for (int mt = 0; mt < 2; ++mt) {
      ah[mt] = AF[(mt*16 + kt)*64 + lane];
      al[mt] = AF[(mt*16 + 8 + kt)*64 + lane];
    }
    __builtin_amdgcn_s_setprio(1);
#pragma unroll
    for (int n = 0; n < 2; ++n)
#pragma unroll
      for (int mt = 0; mt < 2; ++mt) {
        acc[mt][n] = MFMA16(ah[mt], bh[n], acc[mt][n]);
        acc[mt][n] = MFMA16(al[mt], bh[n], acc[mt][n]);
        acc[mt][n] = MFMA16(ah[mt], bl[n], acc[mt][n]);
      }
    __builtin_amdgcn_s_setprio(0);
  }
#pragma unroll
  for (int n = 0; n < 2; ++n) {
    int col = (w*2 + n)*16 + c;
    float bb = bias[col];
#pragma unroll
    for (int mt = 0; mt < 2; ++mt) {
#pragma unroll
      for (int r = 0; r < 4; ++r) {
        int tok = (blockIdx.x*2 + mt)*16 + g*4 + r;
        size_t idx = (size_t)tok*DD + col;
        out[idx] = xres[idx] + acc[mt][n][r] + bb;
      }
    }
  }
}

// ---------------- attention core per (b,h): PV emits hi/lo rows directly ----------------
__global__ __launch_bounds__(256) void k_attn(const float* __restrict__ q, const float* __restrict__ k,
        const float* __restrict__ v, const float* __restrict__ pa, const float* __restrict__ gate_p,
        unsigned short* __restrict__ ahi, unsigned short* __restrict__ alo) {
  int bh = blockIdx.x;
  int b = bh >> 2, hd = bh & 3;
  __shared__ float qs[32][65];
  __shared__ float ks[32][65];
  __shared__ float vs[32][64];
  __shared__ float ssm[32][33];
  __shared__ float pas[32];
  int tid = threadIdx.x;
  const float* qb = q + (size_t)bh * (SS*DHH);
  const float* kb = k + (size_t)bh * (SS*DHH);
  const float* vb = v + (size_t)bh * (SS*DHH);
  for (int it = tid; it < 512; it += 256) {
    int row = it >> 4, col = (it & 15) * 4;
    float4 qv = *reinterpret_cast<const float4*>(qb + row*DHH + col);
    float4 kv = *reinterpret_cast<const float4*>(kb + row*DHH + col);
    float4 vv = *reinterpret_cast<const float4*>(vb + row*DHH + col);
    qs[row][col] = qv.x; qs[row][col+1] = qv.y; qs[row][col+2] = qv.z; qs[row][col+3] = qv.w;
    ks[row][col] = kv.x; ks[row][col+1] = kv.y; ks[row][col+2] = kv.z; ks[row][col+3] = kv.w;
    *reinterpret_cast<float4*>(&vs[row][col]) = vv;
  }
  if (tid < 32) pas[tid] = pa[(size_t)bh * SS + tid];
  __syncthreads();
#pragma unroll
  for (int rr = 0; rr < 4; ++rr) {
    int id = tid + 256*rr;
    int i = id >> 5, j = id & 31;
    float acc = 0.f;
#pragma unroll
    for (int d = 0; d < 64; ++d) acc += qs[i][d] * ks[j][d];
    ssm[i][j] = acc * 0.125f;
  }
  __syncthreads();
  float gs = 1.f / (1.f + expf(-gate_p[hd]));
  float ga = 1.f - gs;
  {
    int i = tid >> 3, sub = tid & 7;   // 8 threads per row, all 256 active
    float v0 = ssm[i][sub*4+0], v1 = ssm[i][sub*4+1];
    float v2 = ssm[i][sub*4+2], v3 = ssm[i][sub*4+3];
    float mx = fmaxf(fmaxf(v0, v1), fmaxf(v2, v3));
#pragma unroll
    for (int off = 1; off < 8; off <<= 1) mx = fmaxf(mx, __shfl_xor(mx, off, 64));
    float e0 = expf(v0-mx), e1 = expf(v1-mx), e2 = expf(v2-mx), e3 = expf(v3-mx);
    float s = e0 + e1 + e2 + e3;
#pragma unroll
    for (int off = 1; off < 8; off <<= 1) s += __shfl_xor(s, off, 64);
    float inv = 1.f / s;
    ssm[i][sub*4+0] = ga*e0*inv + gs*pas[sub*4+0];
    ssm[i][sub*4+1] = ga*e1*inv + gs*pas[sub*4+1];
    ssm[i][sub*4+2] = ga*e2*inv + gs*pas[sub*4+2];
    ssm[i][sub*4+3] = ga*e3*inv + gs*pas[sub*4+3];
  }
  __syncthreads();
  // PV: thread (wave w, lane) owns token mt*16+c, dims ktl*32+g*8..+7 of this head
  {
    int w = tid >> 6, lane = tid & 63;
    int mt = w & 1, ktl = w >> 1;
    int c = lane & 15, g = lane >> 4;
    int tokl = mt*16 + c;
    int dbase = ktl*32 + g*8;
    float acc[8] = {};
#pragma unroll
    for (int j = 0; j < 32; ++j) {
      float s = ssm[tokl][j];
      float4 va = *reinterpret_cast<float4*>(&vs[j][dbase]);
      float4 vb2 = *reinterpret_cast<float4*>(&vs[j][dbase+4]);
      acc[0] += s*va.x;  acc[1] += s*va.y;  acc[2] += s*va.z;  acc[3] += s*va.w;
      acc[4] += s*vb2.x; acc[5] += s*vb2.y; acc[6] += s*vb2.z; acc[7] += s*vb2.w;
    }
    short8 hi, lo;
#pragma unroll
    for (int j = 0; j < 8; ++j) {
      unsigned short hb = f2b(acc[j]);
      hi[j] = (short)hb;
      lo[j] = (short)f2b(acc[j] - b2f(hb));
    }
    size_t base = ((size_t)(b*SS + tokl))*DD + hd*DHH + dbase;
    *reinterpret_cast<short8*>(ahi + base) = hi;
    *reinterpret_cast<short8*>(alo + base) = lo;
  }
}

// ---------------- LN2 + gate logits + top-2 (fp32 routing, bf16 token emit) ----------------
__global__ void k_gate(const float* __restrict__ xo, const float* __restrict__ w,
                       const float* __restrict__ b, const float* __restrict__ wg,
                       unsigned short* __restrict__ flatb, int* __restrict__ topi,
                       float* __restrict__ gates) {
  int t = blockIdx.x * 4 + (threadIdx.x >> 6);
  int lane = threadIdx.x & 63;
  float4 xv = reinterpret_cast<const float4*>(xo + (size_t)t * DD)[lane];
  float s1 = xv.x + xv.y + xv.z + xv.w;
  float s2 = xv.x*xv.x + xv.y*xv.y + xv.z*xv.z + xv.w*xv.w;
  s1 = wred(s1); s2 = wred(s2);
  float m = s1 * (1.f/256.f);
  float var = s2 * (1.f/256.f) - m*m;
  float rs = rsqrtf(var + 1e-6f);
  float4 wv = reinterpret_cast<const float4*>(w)[lane];
  float4 bv = reinterpret_cast<const float4*>(b)[lane];
  float4 fv;
  fv.x = (xv.x-m)*rs*wv.x + bv.x;
  fv.y = (xv.y-m)*rs*wv.y + bv.y;
  fv.z = (xv.z-m)*rs*wv.z + bv.z;
  fv.w = (xv.w-m)*rs*wv.w + bv.w;
  ushort4 fb;
  fb.x = f2b(fv.x); fb.y = f2b(fv.y); fb.z = f2b(fv.z); fb.w = f2b(fv.w);
  *reinterpret_cast<ushort4*>(flatb + (size_t)t * DD + lane*4) = fb;
  float pe[8] = {};
  const float* wgp = wg + lane*4*EE;
#pragma unroll
  for (int dd = 0; dd < 4; ++dd) {
    float fd = f4c(fv, dd);
#pragma unroll
    for (int e2 = 0; e2 < 8; ++e2) pe[e2] += fd * wgp[dd*EE + e2];
  }
#pragma unroll
  for (int off = 32; off; off >>= 1) {
#pragma unroll
    for (int e2 = 0; e2 < 8; ++e2) pe[e2] += __shfl_xor(pe[e2], off, 64);
  }
  if (lane == 0) {
    float best = -1e30f, second = -1e30f; int bi = 0, si = 0;
#pragma unroll
    for (int e2 = 0; e2 < 8; ++e2) {
      float vv = pe[e2];
      if (vv > best) { second = best; si = bi; best = vv; bi = e2; }
      else if (vv > second) { second = vv; si = e2; }
    }
    float e1 = expf(second - best);
    float inv = 1.f / (1.f + e1);
    topi[t*2+0] = bi; topi[t*2+1] = si;
    gates[t*2+0] = inv; gates[t*2+1] = e1 * inv;
  }
}

// ---------------- dispatch: histogram, then self-scanning position kernel ----------------
__global__ void k_hist(const int* __restrict__ topi, int* __restrict__ bc) {
  __shared__ int cnt[EE];
  int tid = threadIdx.x;
  if (tid < EE) cnt[tid] = 0;
  __syncthreads();
  int e = topi[blockIdx.x*256 + tid];
  atomicAdd(&cnt[e], 1);
  __syncthreads();
  if (tid < EE) bc[blockIdx.x*EE + tid] = cnt[tid];
}

// k_disp with fused scan: each block computes its own expert prefix over bc
// (32-lane-group reduction), block 0 also writes per-expert totals to cnt.
__global__ void k_disp(const int* __restrict__ topi, const int* __restrict__ bc,
                       int* __restrict__ ltok, int* __restrict__ slotof,
                       int* __restrict__ cnt) {
  __shared__ int offs[EE];
  __shared__ int wcnt[4][EE];
  int tid = threadIdx.x;
  {
    int e = tid >> 5, l32 = tid & 31;   // 8 groups x 32 lanes
    int sumP = 0, sumT = 0;
#pragma unroll
    for (int it = 0; it < 4; ++it) {
      int blk = l32 + it*32;
      int vv = bc[blk*EE + e];
      sumT += vv;
      if (blk < blockIdx.x) sumP += vv;
    }
#pragma unroll
    for (int off = 1; off < 32; off <<= 1) {
      sumP += __shfl_xor(sumP, off, 32);
      sumT += __shfl_xor(sumT, off, 32);
    }
    if (l32 == 0) {
      offs[e] = sumP;
      if (blockIdx.x == 0) cnt[e] = sumT;
    }
  }
  __syncthreads();
  int i = blockIdx.x*256 + tid;
  int e = topi[i];
  int wv = tid >> 6, lane = tid & 63;
  unsigned long long lt = (1ull << lane) - 1ull;
  int prefix = 0;
#pragma unroll
  for (int ee = 0; ee < EE; ++ee) {
    unsigned long long mb = __ballot(e == ee);
    if (e == ee) prefix = __popcll(mb & lt);
    if (lane == 0) wcnt[wv][ee] = __popcll(mb);
  }
  __syncthreads();
  int off = offs[e];
  for (int w2 = 0; w2 < wv; ++w2) off += wcnt[w2][e];
  int pos = off + prefix;
  if (pos < CAP) { ltok[e*CAP + pos] = i >> 1; slotof[i] = e*CAP + pos; }
  else           { slotof[i] = -1; }
}

// ---------------- MFMA expert FFN v16: 32-token tiles, R12 schedule, 4 blocks/CU ----------------
// LDS 32KB (AsV 16 + H1 dbuf 16) -> 4 blocks/CU = full 32 waves/CU occupancy.
// Per-wave state strictly below R12: y[4]=16, hacc[2]=8, wf[4]=16, wg2r=32.
__global__ __launch_bounds__(512, 4) void k_expert(
    const unsigned short* __restrict__ flatb, const unsigned short* __restrict__ w1s,
    const float* __restrict__ b1, const unsigned short* __restrict__ w2s,
    const float* __restrict__ b2,
    const int* __restrict__ ltok, const int* __restrict__ cnt,
    unsigned short* __restrict__ ybuf) {
  int e = blockIdx.x & 7;          // expert -> XCD pinning (L2 locality)
  int rt0 = blockIdx.x >> 3;       // 0..255
  int kept = cnt[e]; if (kept > CAP) kept = CAP;
  int r0 = rt0 * 32;
  if (r0 >= kept) return;
  __shared__ short8 AsV[1024];     // 16KB token tile [32 rows][32 chunks], swizzled
  __shared__ short8 H1V[1024];     // 16KB h1 double-buffer (2 x 8KB: [32 tok][16 chunks])
  int tid = threadIdx.x;           // 0..511
  int lane = tid & 63;
  int w = tid >> 6;                // wave 0..7
  int c = lane & 15, g = lane >> 4;
  int ts = w & 1, dq = w >> 1;     // GEMM2 roles: tok-half (16), dd-quarter
  // ---- gather 32 token rows (bf16), swizzled chunks
  {
    const short8* fb = reinterpret_cast<const short8*>(flatb);
#pragma unroll
    for (int it = 0; it < 2; ++it) {
      int id = tid + it*512;
      int row = id >> 5, ch = id & 31;
      int rr = r0 + row;
      int src = (rr < kept) ? rr : r0;
      int tok = ltok[e*CAP + src];
      AsV[row*32 + (ch ^ (row & 7))] = fb[(size_t)tok*32 + ch];
    }
  }
  const short8* w1v = reinterpret_cast<const short8*>(w1s);
  const short8* w2v = reinterpret_cast<const short8*>(w2s);
  f32x4 y[4] = {};
  __syncthreads();
  for (int hc = 0; hc < 8; ++hc) {
    f32x4 hacc[2] = {};
    // ---- GEMM1 in two 4-kt halves (wf transient = 16 regs); wave owns hid slice hc*8+w
#pragma unroll
    for (int half = 0; half < 2; ++half) {
      short8 wf[4];
#pragma unroll
      for (int i = 0; i < 4; ++i)
        wf[i] = w1v[((size_t)(e*8 + half*4 + i)*64 + hc*8 + w)*64 + lane];
#pragma unroll
      for (int i = 0; i < 4; ++i) {
        int kt = half*4 + i;
        __builtin_amdgcn_s_setprio(1);
#pragma unroll
        for (int ctT = 0; ctT < 2; ++ctT) {
          short8 a = AsV[(ctT*16 + c)*32 + ((kt*4 + g) ^ (c & 7))];
          hacc[ctT] = MFMA16(wf[i], a, hacc[ctT]);
        }
        __builtin_amdgcn_s_setprio(0);
      }
    }
    float4 b1v = *reinterpret_cast<const float4*>(b1 + e*HID + hc*128 + w*16 + g*4);
    // ---- gelu + pack -> H1V[hc&1]
    {
      uint2* h1u = reinterpret_cast<uint2*>(H1V + (hc & 1)*512);
#pragma unroll
      for (int ctT = 0; ctT < 2; ++ctT) {
        float v0 = gelu_f(hacc[ctT][0] + b1v.x);
        float v1 = gelu_f(hacc[ctT][1] + b1v.y);
        float v2 = gelu_f(hacc[ctT][2] + b1v.z);
        float v3 = gelu_f(hacc[ctT][3] + b1v.w);
        uint2 pk;
        pk.x = cvt_pk_bf16(v0, v1);
        pk.y = cvt_pk_bf16(v2, v3);
        int tok = ctT*16 + c;
        h1u[(tok*32 + w*4 + g) ^ ((c & 7) << 1)] = pk;
      }
    }
    // ---- prefetch GEMM2 hk=0 weights; the barrier wait hides the L2 latency
    short8 wg2r[2][4];
#pragma unroll
    for (int ct = 0; ct < 4; ++ct)
      wg2r[0][ct] = w2v[((size_t)(e*32 + hc*4 + 0)*16 + dq*4 + ct)*64 + lane];
    __syncthreads();   // H1V[hc&1] ready (1 barrier/hc; dbuf protects writes)
    // ---- GEMM2 with ring-1 prefetch; wave owns (tok-half ts, dd-quarter dq)
#pragma unroll
    for (int hk = 0; hk < 4; ++hk) {
      if (hk < 3) {
#pragma unroll
        for (int ct = 0; ct < 4; ++ct)
          wg2r[(hk+1)&1][ct] = w2v[((size_t)(e*32 + hc*4 + hk+1)*16 + dq*4 + ct)*64 + lane];
      }
      int row = ts*16 + c;
      short8 a2 = H1V[(hc & 1)*512 + row*16 + ((hk*4 + g) ^ (c & 7))];
      __builtin_amdgcn_s_setprio(1);
#pragma unroll
      for (int ct = 0; ct < 4; ++ct)
        y[ct] = MFMA16(a2, wg2r[hk&1][ct], y[ct]);
      __builtin_amdgcn_s_setprio(0);
    }
  }
  // ---- epilogue: fold bias, store bf16 rows to ybuf
  float bb2[4];
#pragma unroll
  for (int ct = 0; ct < 4; ++ct) bb2[ct] = b2[e*DD + (dq*4 + ct)*16 + c];
#pragma unroll
  for (int q = 0; q < 4; ++q) {
    int tok = ts*16 + g*4 + q;
    if (r0 + tok < kept) {
      size_t base = (size_t)(e*CAP + r0 + tok) * DD;
#pragma unroll
      for (int ct = 0; ct < 4; ++ct) {
        int dd = (dq*4 + ct)*16 + c;
        ybuf[base + dd] = f2b(y[ct][q] + bb2[ct]);
      }
    }
  }
}

// ---------------- combine: out += g0*y[slot0] + g1*y[slot1] ----------------
__global__ void k_comb(const unsigned short* __restrict__ ybuf, const int* __restrict__ slotof,
                       const float* __restrict__ gates, float* __restrict__ out) {
  int t = blockIdx.x * 4 + (threadIdx.x >> 6);
  int lane = threadIdx.x & 63;
  int s0 = slotof[t*2], s1 = slotof[t*2+1];
  float g0 = gates[t*2], g1 = gates[t*2+1];
  float4 o = reinterpret_cast<float4*>(out + (size_t)t*DD)[lane];
  if (s0 >= 0) {
    ushort4 a = reinterpret_cast<const ushort4*>(ybuf + (size_t)s0*DD)[lane];
    o.x += g0*b2f(a.x); o.y += g0*b2f(a.y); o.z += g0*b2f(a.z); o.w += g0*b2f(a.w);
  }
  if (s1 >= 0) {
    ushort4 a = reinterpret_cast<const ushort4*>(ybuf + (size_t)s1*DD)[lane];
    o.x += g1*b2f(a.x); o.y += g1*b2f(a.y); o.z += g1*b2f(a.z); o.w += g1*b2f(a.w);
  }
  reinterpret_cast<float4*>(out + (size_t)t*DD)[lane] = o;
}

extern "C" void kernel_launch(void* const* d_in, const int* in_sizes, int n_in,
                              void* d_out, int out_size, void* d_ws, size_t ws_size,
                              hipStream_t stream) {
  (void)in_sizes; (void)n_in; (void)out_size; (void)ws_size;
  const float* x    = (const float*)d_in[0];
  const float* pos  = (const float*)d_in[1];
  const float* ln1w = (const float*)d_in[2];
  const float* ln1b = (const float*)d_in[3];
  const float* ln2w = (const float*)d_in[4];
  const float* ln2b = (const float*)d_in[5];
  const float* qw   = (const float*)d_in[6];
  const float* kw   = (const float*)d_in[7];
  const float* vw   = (const float*)d_in[8];
  const float* p1w  = (const float*)d_in[9];
  const float* p1b  = (const float*)d_in[10];
  const float* p2w  = (const float*)d_in[11];
  const float* p2b  = (const float*)d_in[12];
  const float* headw= (const float*)d_in[13];
  const float* gatep= (const float*)d_in[15];
  const float* outw = (const float*)d_in[16];
  const float* outb = (const float*)d_in[17];
  const float* wg   = (const float*)d_in[18];
  const float* ew1  = (const float*)d_in[19];
  const float* eb1  = (const float*)d_in[20];
  const float* ew2  = (const float*)d_in[21];
  const float* eb2  = (const float*)d_in[22];
  float* out = (float*)d_out;

  float* wsf  = (float*)d_ws;
  unsigned short* rhi = (unsigned short*)wsf;             // TD ushorts = 8MB
  unsigned short* rlo = rhi + TD;                         // 8MB
  float* qb   = wsf + TD;
  float* kb   = wsf + 2*TD;
  float* vb   = wsf + 3*TD;
  unsigned short* ybuf = (unsigned short*)(wsf + TD);     // reuses qb+kb after attn
  unsigned short* flatb = (unsigned short*)(wsf + 4*TD);  // 8MB
  unsigned short* w1s   = flatb + TD;                     // 4MB
  unsigned short* w2s   = w1s + (size_t)EE*DD*HID;        // 4MB
  float* pa   = wsf + 5*TD;            // 65536
  float* gates= pa + 65536;            // 32768
  int* topi   = (int*)(gates + 32768); // 32768
  int* ltok   = topi + 32768;          // 65536
  int* bc     = ltok + 65536;          // 1024
  int* bo     = bc + 1024;             // 1024 (unused)
  int* cnt    = bo + 1024;             // 8
  int* slotof = cnt + 8;               // 32768
  unsigned short* wqkvf = (unsigned short*)(wsf + 5*TD + (1<<20));
  unsigned short* woutf = wqkvf + 393216;

  k_prep<<<dim3(6784), dim3(256), 0, stream>>>(
      ew1, w1s, ew2, w2s, qw, kw, vw, wqkvf, outw, woutf,
      pos, p1w, p1b, p2w, p2b, headw, pa,
      x, ln1w, ln1b, rhi, rlo);
  k_qkvm<<<dim3(TT/32), dim3(512), 0, stream>>>(rhi, rlo, wqkvf, qb, kb, vb);
  k_attn<<<dim3(BB*HH), dim3(256), 0, stream>>>(qb, kb, vb, pa, gatep, rhi, rlo);
  k_outm<<<dim3(TT/32), dim3(512), 0, stream>>>(rhi, rlo, woutf, x, outb, out);
  k_gate<<<dim3(TT/4), dim3(256), 0, stream>>>(out, ln2w, ln2b, wg, flatb, topi, gates);
  k_hist<<<dim3(128), dim3(256), 0, stream>>>(topi, bc);
  k_disp<<<dim3(128), dim3(256), 0, stream>>>(topi, bc, ltok, slotof, cnt);
  k_expert<<<dim3(EE*256), dim3(512), 0, stream>>>(flatb, w1s, eb1, w2s, eb2,
                                                   ltok, cnt, ybuf);
  k_comb<<<dim3(TT/4), dim3(256), 0, stream>>>(ybuf, slotof, gates, out);
}

// Round 17
// 180.095 us; speedup vs baseline: 1.0592x; 1.0592x over previous
//
#include <hip/hip_runtime.h>
#include <hip/hip_bf16.h>
#include <math.h>

// Problem constants
#define BB 512
#define SS 32
#define DD 256
#define HH 4
#define DHH 64
#define PP 3
#define EE 8
#define KTOP 2
#define HID 1024
#define TT (BB*SS)          // 16384
#define CAP 8192            // 2*T*K/E
#define TD ((size_t)TT*DD)  // 4194304

typedef short short8 __attribute__((ext_vector_type(8)));
typedef float f32x4 __attribute__((ext_vector_type(4)));

#define GLL(gp, lp) __builtin_amdgcn_global_load_lds( \
    (const __attribute__((address_space(1))) void*)(gp), \
    (__attribute__((address_space(3))) void*)(lp), 16, 0, 0)

#define MFMA16(A, B, C) __builtin_amdgcn_mfma_f32_16x16x32_bf16(A, B, C, 0, 0, 0)

__device__ __forceinline__ float wred(float v) {
#pragma unroll
  for (int off = 32; off; off >>= 1) v += __shfl_xor(v, off, 64);
  return v;
}

__device__ __forceinline__ float f4c(const float4& f, int u) {
  return (u == 0) ? f.x : (u == 1) ? f.y : (u == 2) ? f.z : f.w;
}

__device__ __forceinline__ unsigned short f2b(float f) {
  union { float f; unsigned u; } x; x.f = f;
  unsigned r = x.u + 0x7fffu + ((x.u >> 16) & 1u);
  return (unsigned short)(r >> 16);
}

__device__ __forceinline__ float b2f(unsigned short u) {
  union { unsigned u; float f; } x; x.u = ((unsigned)u) << 16;
  return x.f;
}

__device__ __forceinline__ unsigned cvt_pk_bf16(float lo, float hi) {
  unsigned r;
  asm("v_cvt_pk_bf16_f32 %0, %1, %2" : "=v"(r) : "v"(lo), "v"(hi));
  return r;
}

// tanh-approx gelu, exp2 form
__device__ __forceinline__ float gelu_f(float x) {
  float x2 = x * x;
  float t2 = x * __builtin_fmaf(x2, 0.102943842f, 2.30212326f);
  float e = __builtin_amdgcn_exp2f(t2);
  float r = __builtin_amdgcn_rcpf(e + 1.f);
  float th = __builtin_fmaf(-2.f, r, 1.f);
  return 0.5f * x * (1.f + th);
}

// ---------------- fused prep: weight cvts + pos-attn + LN1-split ----------------
// blocks [0,1024): ew1 cvt; [1024,2048): ew2 cvt; [2048,2144): qkv w cvt;
// [2144,2176): out w cvt; [2176,2688): pos; [2688,6784): LN1+split
__global__ void k_prep(
    const float* __restrict__ ew1, unsigned short* __restrict__ w1s,
    const float* __restrict__ ew2, unsigned short* __restrict__ w2s,
    const float* __restrict__ qw, const float* __restrict__ kw,
    const float* __restrict__ vw, unsigned short* __restrict__ wqkvf,
    const float* __restrict__ outw, unsigned short* __restrict__ woutf,
    const float* __restrict__ pos, const float* __restrict__ p1w,
    const float* __restrict__ p1b, const float* __restrict__ p2w,
    const float* __restrict__ p2b, const float* __restrict__ headw,
    float* __restrict__ pa,
    const float* __restrict__ x, const float* __restrict__ ln1w,
    const float* __restrict__ ln1b, unsigned short* __restrict__ rhi,
    unsigned short* __restrict__ rlo) {
  __shared__ float shbuf[2*HH*SS];
  int bid = blockIdx.x;
  int tid = threadIdx.x;
  if (bid < 2048) {
    const float* src = (bid < 1024) ? ew1 : ew2;
    unsigned short* dst = (bid < 1024) ? w1s : w2s;
    int K = (bid < 1024) ? DD : HID;
    int N = (bid < 1024) ? HID : DD;
    int idx = (bid & 1023) * 256 + tid;
    int lane = idx & 63;
    int tile = idx >> 6;
    int ntn = N >> 4;
    int ntk = K >> 5;
    int e = tile / (ntk * ntn);
    int rem = tile - e * (ntk * ntn);
    int kt = rem / ntn;
    int nt = rem - kt * ntn;
    int g = lane >> 4, c = lane & 15;
    const float* s = src + ((size_t)e * K + kt*32 + g*8) * N + nt*16 + c;
    short8 frag;
#pragma unroll
    for (int j = 0; j < 8; ++j) frag[j] = (short)f2b(s[(size_t)j * N]);
    reinterpret_cast<short8*>(dst)[(size_t)tile * 64 + lane] = frag;
  } else if (bid < 2144) {
    int tile = (bid - 2048) * 4 + (tid >> 6);   // kt*48 + nt
    int lane = tid & 63;
    int kt = tile / 48, nt = tile % 48;
    int c = lane & 15, g = lane >> 4;
    const float* W = (nt < 16) ? qw : (nt < 32) ? kw : vw;
    int col = (nt & 15) * 16 + c;
    const float* s = W + ((size_t)kt*32 + g*8)*DD + col;
    short8 hi, lo;
#pragma unroll
    for (int j = 0; j < 8; ++j) {
      float xx = s[(size_t)j * DD];
      unsigned short hb = f2b(xx);
      hi[j] = (short)hb;
      lo[j] = (short)f2b(xx - b2f(hb));
    }
    short8* d = reinterpret_cast<short8*>(wqkvf);
    d[(size_t)tile*128 + lane] = hi;
    d[(size_t)tile*128 + 64 + lane] = lo;
  } else if (bid < 2176) {
    int tile = (bid - 2144) * 4 + (tid >> 6);   // kt*16 + nt
    int lane = tid & 63;
    int kt = tile >> 4, nt = tile & 15;
    int c = lane & 15, g = lane >> 4;
    int col = nt * 16 + c;
    const float* s = outw + ((size_t)kt*32 + g*8)*DD + col;
    short8 hi, lo;
#pragma unroll
    for (int j = 0; j < 8; ++j) {
      float xx = s[(size_t)j * DD];
      unsigned short hb = f2b(xx);
      hi[j] = (short)hb;
      lo[j] = (short)f2b(xx - b2f(hb));
    }
    short8* d = reinterpret_cast<short8*>(woutf);
    d[(size_t)tile*128 + lane] = hi;
    d[(size_t)tile*128 + 64 + lane] = lo;
  } else if (bid < 2688) {
    int b = bid - 2176;
    float* ph = shbuf;
    float* ex = shbuf + HH*SS;
    if (tid < 128) {
      int s = tid >> 2, hd = tid & 3;
      const float* pp = pos + ((size_t)b * SS + s) * PP;
      float p0 = pp[0], p1 = pp[1], p2 = pp[2];
      float t0 = fmaxf(0.f, p0*p1w[0] + p1*p1w[3] + p2*p1w[6] + p1b[0]);
      float t1 = fmaxf(0.f, p0*p1w[1] + p1*p1w[4] + p2*p1w[7] + p1b[1]);
      float t2 = fmaxf(0.f, p0*p1w[2] + p1*p1w[5] + p2*p1w[8] + p1b[2]);
      float acc = 0.f;
#pragma unroll
      for (int c = 0; c < 32; ++c) {
        float pf = t0*p2w[c] + t1*p2w[32+c] + t2*p2w[64+c] + p2b[c];
        acc += pf * headw[c*4 + hd];
      }
      ph[hd*SS + s] = acc;
    }
    __syncthreads();
    if (tid < 4) {
      int h2 = tid;
      float mx = -1e30f;
      for (int j = 0; j < 32; ++j) mx = fmaxf(mx, -ph[h2*SS + j]);
      float sum = 0.f;
      for (int j = 0; j < 32; ++j) { float e = expf(-ph[h2*SS + j] - mx); ex[h2*SS + j] = e; sum += e; }
      float inv = 1.f / sum;
      for (int j = 0; j < 32; ++j) pa[((size_t)b*HH + h2)*SS + j] = ex[h2*SS + j] * inv;
    }
  } else {
    int t = (bid - 2688) * 4 + (tid >> 6);
    int lane = tid & 63;
    float4 xv = reinterpret_cast<const float4*>(x + (size_t)t * DD)[lane];
    float s1 = xv.x + xv.y + xv.z + xv.w;
    float s2 = xv.x*xv.x + xv.y*xv.y + xv.z*xv.z + xv.w*xv.w;
    s1 = wred(s1); s2 = wred(s2);
    float m = s1 * (1.f/256.f);
    float var = s2 * (1.f/256.f) - m*m;
    float rs = rsqrtf(var + 1e-6f);
    float4 wv = reinterpret_cast<const float4*>(ln1w)[lane];
    float4 bv = reinterpret_cast<const float4*>(ln1b)[lane];
    float4 o;
    o.x = (xv.x-m)*rs*wv.x + bv.x;
    o.y = (xv.y-m)*rs*wv.y + bv.y;
    o.z = (xv.z-m)*rs*wv.z + bv.z;
    o.w = (xv.w-m)*rs*wv.w + bv.w;
    ushort4 h4, l4;
    h4.x = f2b(o.x); l4.x = f2b(o.x - b2f(h4.x));
    h4.y = f2b(o.y); l4.y = f2b(o.y - b2f(h4.y));
    h4.z = f2b(o.z); l4.z = f2b(o.z - b2f(h4.z));
    h4.w = f2b(o.w); l4.w = f2b(o.w - b2f(h4.w));
    *reinterpret_cast<ushort4*>(rhi + (size_t)t * DD + lane*4) = h4;
    *reinterpret_cast<ushort4*>(rlo + (size_t)t * DD + lane*4) = l4;
  }
}

// ---------------- QKV via split-bf16 MFMA, M=32; A gathered per-lane via GLL ----------------
__global__ __launch_bounds__(512, 4) void k_qkvm(
    const unsigned short* __restrict__ hr, const unsigned short* __restrict__ lr,
    const unsigned short* __restrict__ wqkvf,
    float* __restrict__ q, float* __restrict__ k, float* __restrict__ v) {
  __shared__ short8 AF[2048];             // 32KB: 2 mt x (hi 8 + lo 8 kt) x 64
  int tid = threadIdx.x, lane = tid & 63, w = tid >> 6;
  int c = lane & 15, g = lane >> 4;
#pragma unroll
  for (int i = 0; i < 4; ++i) {
    int comb = i*8 + w;                   // 0..31
    int mt = comb >> 4, slot = comb & 15;
    int kt = slot & 7;
    const unsigned short* src = (slot < 8) ? hr : lr;
    const unsigned short* sp = src + ((size_t)(blockIdx.x*32 + mt*16 + c)*DD + kt*32 + g*8);
    GLL(sp, AF + comb*64);
  }
  const short8* wfv = reinterpret_cast<const short8*>(wqkvf);
  f32x4 acc[2][6] = {};
  __syncthreads();
#pragma unroll
  for (int kt = 0; kt < 8; ++kt) {
    short8 bh[6], bl[6];
#pragma unroll
    for (int n = 0; n < 6; ++n) {
      const short8* bp = wfv + ((size_t)kt*48 + w*6 + n)*128;
      bh[n] = bp[lane]; bl[n] = bp[64 + lane];
    }
    short8 ah[2], al[2];
#pragma unroll
    for (int mt = 0; mt < 2; ++mt) {
      ah[mt] = AF[(mt*16 + kt)*64 + lane];
      al[mt] = AF[(mt*16 + 8 + kt)*64 + lane];
    }
    __builtin_amdgcn_s_setprio(1);
#pragma unroll
    for (int n = 0; n < 6; ++n)
#pragma unroll
      for (int mt = 0; mt < 2; ++mt) {
        acc[mt][n] = MFMA16(ah[mt], bh[n], acc[mt][n]);
        acc[mt][n] = MFMA16(al[mt], bh[n], acc[mt][n]);
        acc[mt][n] = MFMA16(ah[mt], bl[n], acc[mt][n]);
      }
    __builtin_amdgcn_s_setprio(0);
  }
#pragma unroll
  for (int n = 0; n < 6; ++n) {
    int col = w*96 + n*16 + c;
    int wsel = col >> 8, cc = col & 255;
    int hd = cc >> 6, d2 = cc & 63;
    float* OUT = (wsel == 0) ? q : (wsel == 1) ? k : v;
#pragma unroll
    for (int mt = 0; mt < 2; ++mt) {
#pragma unroll
      for (int r = 0; r < 4; ++r) {
        int tok = (blockIdx.x*2 + mt)*16 + g*4 + r;
        int b = tok >> 5, s = tok & 31;
        OUT[(((size_t)b*HH + hd)*SS + s)*DHH + d2] = acc[mt][n][r];
      }
    }
  }
}

// ---------------- out-proj via split-bf16 MFMA + residual, M=32, GLL gather ----------------
__global__ __launch_bounds__(512, 4) void k_outm(
    const unsigned short* __restrict__ hr, const unsigned short* __restrict__ lr,
    const unsigned short* __restrict__ wof,
    const float* __restrict__ xres, const float* __restrict__ bias,
    float* __restrict__ out) {
  __shared__ short8 AF[2048];             // 32KB
  int tid = threadIdx.x, lane = tid & 63, w = tid >> 6;
  int c = lane & 15, g = lane >> 4;
#pragma unroll
  for (int i = 0; i < 4; ++i) {
    int comb = i*8 + w;
    int mt = comb >> 4, slot = comb & 15;
    int kt = slot & 7;
    const unsigned short* src = (slot < 8) ? hr : lr;
    const unsigned short* sp = src + ((size_t)(blockIdx.x*32 + mt*16 + c)*DD + kt*32 + g*8);
    GLL(sp, AF + comb*64);
  }
  const short8* wfv = reinterpret_cast<const short8*>(wof);
  f32x4 acc[2][2] = {};
  __syncthreads();
#pragma unroll
  for (int kt = 0; kt < 8; ++kt) {
    short8 bh[2], bl[2];
#pragma unroll
    for (int n = 0; n < 2; ++n) {
      const short8* bp = wfv + ((size_t)kt*16 + w*2 + n)*128;
      bh[n] = bp[lane]; bl[n] = bp[64 + lane];
    }
    short8 ah[2], al[2];
#pragma unroll
    for (int mt = 0; mt < 2; ++mt) {
      ah[mt] = AF[(mt*16 + kt)*64 + lane];
      al[mt] = AF[(mt*16 + 8 + kt)*64 + lane];
    }
    __builtin_amdgcn_s_setprio(1);
#pragma unroll
    for (int n = 0; n < 2; ++n)
#pragma unroll
      for (int mt = 0; mt < 2; ++mt) {
        acc[mt][n] = MFMA16(ah[mt], bh[n], acc[mt][n]);
        acc[mt][n] = MFMA16(al[mt], bh[n], acc[mt][n]);
        acc[mt][n] = MFMA16(ah[mt], bl[n], acc[mt][n]);
      }
    __builtin_amdgcn_s_setprio(0);
  }
#pragma unroll
  for (int n = 0; n < 2; ++n) {
    int col = (w*2 + n)*16 + c;
    float bb = bias[col];
#pragma unroll
    for (int mt = 0; mt < 2; ++mt) {
#pragma unroll
      for (int r = 0; r < 4; ++r) {
        int tok = (blockIdx.x*2 + mt)*16 + g*4 + r;
        size_t idx = (size_t)tok*DD + col;
        out[idx] = xres[idx] + acc[mt][n][r] + bb;
      }
    }
  }
}

// ---------------- attention core per (b,h): PV emits hi/lo rows directly ----------------
__global__ __launch_bounds__(256) void k_attn(const float* __restrict__ q, const float* __restrict__ k,
        const float* __restrict__ v, const float* __restrict__ pa, const float* __restrict__ gate_p,
        unsigned short* __restrict__ ahi, unsigned short* __restrict__ alo) {
  int bh = blockIdx.x;
  int b = bh >> 2, hd = bh & 3;
  __shared__ float qs[32][65];
  __shared__ float ks[32][65];
  __shared__ float vs[32][64];
  __shared__ float ssm[32][33];
  __shared__ float pas[32];
  int tid = threadIdx.x;
  const float* qb = q + (size_t)bh * (SS*DHH);
  const float* kb = k + (size_t)bh * (SS*DHH);
  const float* vb = v + (size_t)bh * (SS*DHH);
  for (int it = tid; it < 512; it += 256) {
    int row = it >> 4, col = (it & 15) * 4;
    float4 qv = *reinterpret_cast<const float4*>(qb + row*DHH + col);
    float4 kv = *reinterpret_cast<const float4*>(kb + row*DHH + col);
    float4 vv = *reinterpret_cast<const float4*>(vb + row*DHH + col);
    qs[row][col] = qv.x; qs[row][col+1] = qv.y; qs[row][col+2] = qv.z; qs[row][col+3] = qv.w;
    ks[row][col] = kv.x; ks[row][col+1] = kv.y; ks[row][col+2] = kv.z; ks[row][col+3] = kv.w;
    *reinterpret_cast<float4*>(&vs[row][col]) = vv;
  }
  if (tid < 32) pas[tid] = pa[(size_t)bh * SS + tid];
  __syncthreads();
#pragma unroll
  for (int rr = 0; rr < 4; ++rr) {
    int id = tid + 256*rr;
    int i = id >> 5, j = id & 31;
    float acc = 0.f;
#pragma unroll
    for (int d = 0; d < 64; ++d) acc += qs[i][d] * ks[j][d];
    ssm[i][j] = acc * 0.125f;
  }
  __syncthreads();
  float gs = 1.f / (1.f + expf(-gate_p[hd]));
  float ga = 1.f - gs;
  {
    int i = tid >> 3, sub = tid & 7;   // 8 threads per row, all 256 active
    float v0 = ssm[i][sub*4+0], v1 = ssm[i][sub*4+1];
    float v2 = ssm[i][sub*4+2], v3 = ssm[i][sub*4+3];
    float mx = fmaxf(fmaxf(v0, v1), fmaxf(v2, v3));
#pragma unroll
    for (int off = 1; off < 8; off <<= 1) mx = fmaxf(mx, __shfl_xor(mx, off, 64));
    float e0 = expf(v0-mx), e1 = expf(v1-mx), e2 = expf(v2-mx), e3 = expf(v3-mx);
    float s = e0 + e1 + e2 + e3;
#pragma unroll
    for (int off = 1; off < 8; off <<= 1) s += __shfl_xor(s, off, 64);
    float inv = 1.f / s;
    ssm[i][sub*4+0] = ga*e0*inv + gs*pas[sub*4+0];
    ssm[i][sub*4+1] = ga*e1*inv + gs*pas[sub*4+1];
    ssm[i][sub*4+2] = ga*e2*inv + gs*pas[sub*4+2];
    ssm[i][sub*4+3] = ga*e3*inv + gs*pas[sub*4+3];
  }
  __syncthreads();
  // PV: thread (wave w, lane) owns token mt*16+c, dims ktl*32+g*8..+7 of this head
  {
    int w = tid >> 6, lane = tid & 63;
    int mt = w & 1, ktl = w >> 1;
    int c = lane & 15, g = lane >> 4;
    int tokl = mt*16 + c;
    int dbase = ktl*32 + g*8;
    float acc[8] = {};
#pragma unroll
    for (int j = 0; j < 32; ++j) {
      float s = ssm[tokl][j];
      float4 va = *reinterpret_cast<float4*>(&vs[j][dbase]);
      float4 vb2 = *reinterpret_cast<float4*>(&vs[j][dbase+4]);
      acc[0] += s*va.x;  acc[1] += s*va.y;  acc[2] += s*va.z;  acc[3] += s*va.w;
      acc[4] += s*vb2.x; acc[5] += s*vb2.y; acc[6] += s*vb2.z; acc[7] += s*vb2.w;
    }
    short8 hi, lo;
#pragma unroll
    for (int j = 0; j < 8; ++j) {
      unsigned short hb = f2b(acc[j]);
      hi[j] = (short)hb;
      lo[j] = (short)f2b(acc[j] - b2f(hb));
    }
    size_t base = ((size_t)(b*SS + tokl))*DD + hd*DHH + dbase;
    *reinterpret_cast<short8*>(ahi + base) = hi;
    *reinterpret_cast<short8*>(alo + base) = lo;
  }
}

// ---------------- LN2 + gate logits + top-2 (fp32 routing, bf16 token emit) ----------------
__global__ void k_gate(const float* __restrict__ xo, const float* __restrict__ w,
                       const float* __restrict__ b, const float* __restrict__ wg,
                       unsigned short* __restrict__ flatb, int* __restrict__ topi,
                       float* __restrict__ gates) {
  int t = blockIdx.x * 4 + (threadIdx.x >> 6);
  int lane = threadIdx.x & 63;
  float4 xv = reinterpret_cast<const float4*>(xo + (size_t)t * DD)[lane];
  float s1 = xv.x + xv.y + xv.z + xv.w;
  float s2 = xv.x*xv.x + xv.y*xv.y + xv.z*xv.z + xv.w*xv.w;
  s1 = wred(s1); s2 = wred(s2);
  float m = s1 * (1.f/256.f);
  float var = s2 * (1.f/256.f) - m*m;
  float rs = rsqrtf(var + 1e-6f);
  float4 wv = reinterpret_cast<const float4*>(w)[lane];
  float4 bv = reinterpret_cast<const float4*>(b)[lane];
  float4 fv;
  fv.x = (xv.x-m)*rs*wv.x + bv.x;
  fv.y = (xv.y-m)*rs*wv.y + bv.y;
  fv.z = (xv.z-m)*rs*wv.z + bv.z;
  fv.w = (xv.w-m)*rs*wv.w + bv.w;
  ushort4 fb;
  fb.x = f2b(fv.x); fb.y = f2b(fv.y); fb.z = f2b(fv.z); fb.w = f2b(fv.w);
  *reinterpret_cast<ushort4*>(flatb + (size_t)t * DD + lane*4) = fb;
  float pe[8] = {};
  const float* wgp = wg + lane*4*EE;
#pragma unroll
  for (int dd = 0; dd < 4; ++dd) {
    float fd = f4c(fv, dd);
#pragma unroll
    for (int e2 = 0; e2 < 8; ++e2) pe[e2] += fd * wgp[dd*EE + e2];
  }
#pragma unroll
  for (int off = 32; off; off >>= 1) {
#pragma unroll
    for (int e2 = 0; e2 < 8; ++e2) pe[e2] += __shfl_xor(pe[e2], off, 64);
  }
  if (lane == 0) {
    float best = -1e30f, second = -1e30f; int bi = 0, si = 0;
#pragma unroll
    for (int e2 = 0; e2 < 8; ++e2) {
      float vv = pe[e2];
      if (vv > best) { second = best; si = bi; best = vv; bi = e2; }
      else if (vv > second) { second = vv; si = e2; }
    }
    float e1 = expf(second - best);
    float inv = 1.f / (1.f + e1);
    topi[t*2+0] = bi; topi[t*2+1] = si;
    gates[t*2+0] = inv; gates[t*2+1] = e1 * inv;
  }
}

// ---------------- dispatch: histogram, then self-scanning position kernel ----------------
__global__ void k_hist(const int* __restrict__ topi, int* __restrict__ bc) {
  __shared__ int cnt[EE];
  int tid = threadIdx.x;
  if (tid < EE) cnt[tid] = 0;
  __syncthreads();
  int e = topi[blockIdx.x*256 + tid];
  atomicAdd(&cnt[e], 1);
  __syncthreads();
  if (tid < EE) bc[blockIdx.x*EE + tid] = cnt[tid];
}

// k_disp with fused scan: each block computes its own expert prefix over bc
// (32-lane-group reduction), block 0 also writes per-expert totals to cnt.
__global__ void k_disp(const int* __restrict__ topi, const int* __restrict__ bc,
                       int* __restrict__ ltok, int* __restrict__ slotof,
                       int* __restrict__ cnt) {
  __shared__ int offs[EE];
  __shared__ int wcnt[4][EE];
  int tid = threadIdx.x;
  {
    int e = tid >> 5, l32 = tid & 31;   // 8 groups x 32 lanes
    int sumP = 0, sumT = 0;
#pragma unroll
    for (int it = 0; it < 4; ++it) {
      int blk = l32 + it*32;
      int vv = bc[blk*EE + e];
      sumT += vv;
      if (blk < blockIdx.x) sumP += vv;
    }
#pragma unroll
    for (int off = 1; off < 32; off <<= 1) {
      sumP += __shfl_xor(sumP, off, 32);
      sumT += __shfl_xor(sumT, off, 32);
    }
    if (l32 == 0) {
      offs[e] = sumP;
      if (blockIdx.x == 0) cnt[e] = sumT;
    }
  }
  __syncthreads();
  int i = blockIdx.x*256 + tid;
  int e = topi[i];
  int wv = tid >> 6, lane = tid & 63;
  unsigned long long lt = (1ull << lane) - 1ull;
  int prefix = 0;
#pragma unroll
  for (int ee = 0; ee < EE; ++ee) {
    unsigned long long mb = __ballot(e == ee);
    if (e == ee) prefix = __popcll(mb & lt);
    if (lane == 0) wcnt[wv][ee] = __popcll(mb);
  }
  __syncthreads();
  int off = offs[e];
  for (int w2 = 0; w2 < wv; ++w2) off += wcnt[w2][e];
  int pos = off + prefix;
  if (pos < CAP) { ltok[e*CAP + pos] = i >> 1; slotof[i] = e*CAP + pos; }
  else           { slotof[i] = -1; }
}

// ---------------- MFMA expert FFN v12 (best measured): R10 structure + in-hc ring prefetch ----------------
__global__ __launch_bounds__(512, 4) void k_expert(
    const unsigned short* __restrict__ flatb, const unsigned short* __restrict__ w1s,
    const float* __restrict__ b1, const unsigned short* __restrict__ w2s,
    const float* __restrict__ b2,
    const int* __restrict__ ltok, const int* __restrict__ cnt,
    unsigned short* __restrict__ ybuf) {
  int e = blockIdx.x & 7;          // expert -> XCD pinning (L2 locality)
  int rt0 = blockIdx.x >> 3;
  int kept = cnt[e]; if (kept > CAP) kept = CAP;
  int r0 = rt0 * 64;
  if (r0 >= kept) return;
  __shared__ short8 AsV[2048];     // 32KB token tile, XOR-swizzled 16B chunks
  __shared__ short8 H1V[2048];     // 32KB h1 double-buffer (2 x 16KB)
  int tid = threadIdx.x;           // 0..511
  int lane = tid & 63;
  int w = tid >> 6;                // wave 0..7
  int c = lane & 15, g = lane >> 4;
  int ts = w & 1, dq = w >> 1;     // GEMM2 roles: tok-half, dd-quarter
  {
    const short8* fb = reinterpret_cast<const short8*>(flatb);
#pragma unroll
    for (int it = 0; it < 4; ++it) {
      int id = tid + it*512;
      int row = id >> 5, ch = id & 31;
      int rr = r0 + row;
      int src = (rr < kept) ? rr : r0;
      int tok = ltok[e*CAP + src];
      AsV[row*32 + (ch ^ (row & 7))] = fb[(size_t)tok*32 + ch];
    }
  }
  const short8* w1v = reinterpret_cast<const short8*>(w1s);
  const short8* w2v = reinterpret_cast<const short8*>(w2s);
  f32x4 y[2][4] = {};
  __syncthreads();
  for (int hc = 0; hc < 8; ++hc) {
    f32x4 hacc[4] = {};
    // ---- GEMM1 in two 4-kt halves (wf transient = 16 regs)
#pragma unroll
    for (int half = 0; half < 2; ++half) {
      short8 wf[4];
#pragma unroll
      for (int i = 0; i < 4; ++i)
        wf[i] = w1v[((size_t)(e*8 + half*4 + i)*64 + hc*8 + w)*64 + lane];
#pragma unroll
      for (int i = 0; i < 4; ++i) {
        int kt = half*4 + i;
        __builtin_amdgcn_s_setprio(1);
#pragma unroll
        for (int ctT = 0; ctT < 4; ++ctT) {
          short8 a = AsV[(ctT*16 + c)*32 + ((kt*4 + g) ^ (c & 7))];
          hacc[ctT] = MFMA16(wf[i], a, hacc[ctT]);
        }
        __builtin_amdgcn_s_setprio(0);
      }
    }
    float4 b1v = *reinterpret_cast<const float4*>(b1 + e*HID + hc*128 + w*16 + g*4);
    // ---- gelu + pack -> H1V[hc&1]
    {
      uint2* h1u = reinterpret_cast<uint2*>(H1V + (hc & 1)*1024);
#pragma unroll
      for (int ctT = 0; ctT < 4; ++ctT) {
        float v0 = gelu_f(hacc[ctT][0] + b1v.x);
        float v1 = gelu_f(hacc[ctT][1] + b1v.y);
        float v2 = gelu_f(hacc[ctT][2] + b1v.z);
        float v3 = gelu_f(hacc[ctT][3] + b1v.w);
        uint2 pk;
        pk.x = cvt_pk_bf16(v0, v1);
        pk.y = cvt_pk_bf16(v2, v3);
        int tok = ctT*16 + c;
        h1u[(tok*32 + w*4 + g) ^ ((c & 7) << 1)] = pk;
      }
    }
    // ---- prefetch GEMM2 hk=0 weights; the barrier wait hides the L2 latency
    short8 wg2r[2][4];
#pragma unroll
    for (int ct = 0; ct < 4; ++ct)
      wg2r[0][ct] = w2v[((size_t)(e*32 + hc*4 + 0)*16 + dq*4 + ct)*64 + lane];
    __syncthreads();   // H1V[hc&1] ready
    // ---- GEMM2 with ring-1 prefetch (confined to this hc)
#pragma unroll
    for (int hk = 0; hk < 4; ++hk) {
      if (hk < 3) {
#pragma unroll
        for (int ct = 0; ct < 4; ++ct)
          wg2r[(hk+1)&1][ct] = w2v[((size_t)(e*32 + hc*4 + hk+1)*16 + dq*4 + ct)*64 + lane];
      }
      short8 a2[2];
#pragma unroll
      for (int rt = 0; rt < 2; ++rt) {
        int row = (ts*2 + rt)*16 + c;
        a2[rt] = H1V[(hc & 1)*1024 + row*16 + ((hk*4 + g) ^ (c & 7))];
      }
      __builtin_amdgcn_s_setprio(1);
#pragma unroll
      for (int ct = 0; ct < 4; ++ct)
#pragma unroll
        for (int rt = 0; rt < 2; ++rt)
          y[rt][ct] = MFMA16(a2[rt], wg2r[hk&1][ct], y[rt][ct]);
      __builtin_amdgcn_s_setprio(0);
    }
  }
  float bb2[4];
#pragma unroll
  for (int ct = 0; ct < 4; ++ct) bb2[ct] = b2[e*DD + (dq*4 + ct)*16 + c];
#pragma unroll
  for (int rt = 0; rt < 2; ++rt) {
#pragma unroll
    for (int q = 0; q < 4; ++q) {
      int tok = (ts*2 + rt)*16 + g*4 + q;
      if (r0 + tok < kept) {
        size_t base = (size_t)(e*CAP + r0 + tok) * DD;
#pragma unroll
        for (int ct = 0; ct < 4; ++ct) {
          int dd = (dq*4 + ct)*16 + c;
          ybuf[base + dd] = f2b(y[rt][ct][q] + bb2[ct]);
        }
      }
    }
  }
}

// ---------------- combine: out += g0*y[slot0] + g1*y[slot1] ----------------
__global__ void k_comb(const unsigned short* __restrict__ ybuf, const int* __restrict__ slotof,
                       const float* __restrict__ gates, float* __restrict__ out) {
  int t = blockIdx.x * 4 + (threadIdx.x >> 6);
  int lane = threadIdx.x & 63;
  int s0 = slotof[t*2], s1 = slotof[t*2+1];
  float g0 = gates[t*2], g1 = gates[t*2+1];
  float4 o = reinterpret_cast<float4*>(out + (size_t)t*DD)[lane];
  if (s0 >= 0) {
    ushort4 a = reinterpret_cast<const ushort4*>(ybuf + (size_t)s0*DD)[lane];
    o.x += g0*b2f(a.x); o.y += g0*b2f(a.y); o.z += g0*b2f(a.z); o.w += g0*b2f(a.w);
  }
  if (s1 >= 0) {
    ushort4 a = reinterpret_cast<const ushort4*>(ybuf + (size_t)s1*DD)[lane];
    o.x += g1*b2f(a.x); o.y += g1*b2f(a.y); o.z += g1*b2f(a.z); o.w += g1*b2f(a.w);
  }
  reinterpret_cast<float4*>(out + (size_t)t*DD)[lane] = o;
}

extern "C" void kernel_launch(void* const* d_in, const int* in_sizes, int n_in,
                              void* d_out, int out_size, void* d_ws, size_t ws_size,
                              hipStream_t stream) {
  (void)in_sizes; (void)n_in; (void)out_size; (void)ws_size;
  const float* x    = (const float*)d_in[0];
  const float* pos  = (const float*)d_in[1];
  const float* ln1w = (const float*)d_in[2];
  const float* ln1b = (const float*)d_in[3];
  const float* ln2w = (const float*)d_in[4];
  const float* ln2b = (const float*)d_in[5];
  const float* qw   = (const float*)d_in[6];
  const float* kw   = (const float*)d_in[7];
  const float* vw   = (const float*)d_in[8];
  const float* p1w  = (const float*)d_in[9];
  const float* p1b  = (const float*)d_in[10];
  const float* p2w  = (const float*)d_in[11];
  const float* p2b  = (const float*)d_in[12];
  const float* headw= (const float*)d_in[13];
  const float* gatep= (const float*)d_in[15];
  const float* outw = (const float*)d_in[16];
  const float* outb = (const float*)d_in[17];
  const float* wg   = (const float*)d_in[18];
  const float* ew1  = (const float*)d_in[19];
  const float* eb1  = (const float*)d_in[20];
  const float* ew2  = (const float*)d_in[21];
  const float* eb2  = (const float*)d_in[22];
  float* out = (float*)d_out;

  float* wsf  = (float*)d_ws;
  unsigned short* rhi = (unsigned short*)wsf;             // TD ushorts = 8MB
  unsigned short* rlo = rhi + TD;                         // 8MB
  float* qb   = wsf + TD;
  float* kb   = wsf + 2*TD;
  float* vb   = wsf + 3*TD;
  unsigned short* ybuf = (unsigned short*)(wsf + TD);     // reuses qb+kb after attn
  unsigned short* flatb = (unsigned short*)(wsf + 4*TD);  // 8MB
  unsigned short* w1s   = flatb + TD;                     // 4MB
  unsigned short* w2s   = w1s + (size_t)EE*DD*HID;        // 4MB
  float* pa   = wsf + 5*TD;            // 65536
  float* gates= pa + 65536;            // 32768
  int* topi   = (int*)(gates + 32768); // 32768
  int* ltok   = topi + 32768;          // 65536
  int* bc     = ltok + 65536;          // 1024
  int* bo     = bc + 1024;             // 1024 (unused)
  int* cnt    = bo + 1024;             // 8
  int* slotof = cnt + 8;               // 32768
  unsigned short* wqkvf = (unsigned short*)(wsf + 5*TD + (1<<20));
  unsigned short* woutf = wqkvf + 393216;

  k_prep<<<dim3(6784), dim3(256), 0, stream>>>(
      ew1, w1s, ew2, w2s, qw, kw, vw, wqkvf, outw, woutf,
      pos, p1w, p1b, p2w, p2b, headw, pa,
      x, ln1w, ln1b, rhi, rlo);
  k_qkvm<<<dim3(TT/32), dim3(512), 0, stream>>>(rhi, rlo, wqkvf, qb, kb, vb);
  k_attn<<<dim3(BB*HH), dim3(256), 0, stream>>>(qb, kb, vb, pa, gatep, rhi, rlo);
  k_outm<<<dim3(TT/32), dim3(512), 0, stream>>>(rhi, rlo, woutf, x, outb, out);
  k_gate<<<dim3(TT/4), dim3(256), 0, stream>>>(out, ln2w, ln2b, wg, flatb, topi, gates);
  k_hist<<<dim3(128), dim3(256), 0, stream>>>(topi, bc);
  k_disp<<<dim3(128), dim3(256), 0, stream>>>(topi, bc, ltok, slotof, cnt);
  k_expert<<<dim3(EE*128), dim3(512), 0, stream>>>(flatb, w1s, eb1, w2s, eb2,
                                                   ltok, cnt, ybuf);
  k_comb<<<dim3(TT/4), dim3(256), 0, stream>>>(ybuf, slotof, gates, out);
}